// Round 3
// baseline (1732.681 us; speedup 1.0000x reference)
//
#include <hip/hip_runtime.h>

// CompetitiveLayer: K = param^2 (4096x4096 f32), 21 fixed-point iterations of
//   AF = AT/(1+K@BF); BF = BT/(1+AF@K)   -> 42 dependent matvec phases,
// then C = K * AF[:,None] * BF[None,:].
//
// R4 theory (still live): R3 proved local work is not the cost (spill fixed,
// VGPR=136, time unchanged at 1605us; VALUBusy 1.2%, HBM 1.2%). The wall is
// ~38us/phase of wait in the single-cacheline grid barrier: 256 device-scope
// fetch_add(ACQ_REL) on ONE line under 256 spinning ACQUIRE readers.
//
// R5 = R4 barrier redesign + hang-hardening (R4 bench died; infra or hang):
//   - arrival: each block t0 RELEASE-stores phase# to its OWN 16B-strided
//     slot, then __threadfence() (s_waitcnt vmcnt(0) -- forces the store
//     globally visible BEFORE entering the spin; relaxed/release stores are
//     not otherwise ordered against the subsequent unbounded load loop).
//   - block 0: 256 threads ACQUIRE-poll the 256 slots in parallel, sync,
//     t0 RELEASE-stores one broadcast word.
//   - others: read-only ACQUIRE spin on the broadcast word. No RMW anywhere.
//   - barrier region shrunk to +4.2KiB past the 3 accumulators (total memset
//     53.4KiB) in case ws_size is tight against the proven ~49KiB footprint.

constexpr int N      = 4096;
constexpr int NPHASE = 42;
constexpr int NBLK   = 256;
constexpr int RREG   = 7;           // subtile rows 0..RREG-1 in VGPRs
constexpr int RLDS   = 16 - RREG;   // subtile rows RREG..15 in LDS

__device__ __forceinline__ float ld_agent(const float* p) {
    return __hip_atomic_load(p, __ATOMIC_RELAXED, __HIP_MEMORY_SCOPE_AGENT);
}
__device__ __forceinline__ void st_agent(float* p, float v) {
    __hip_atomic_store(p, v, __ATOMIC_RELAXED, __HIP_MEMORY_SCOPE_AGENT);
}

// Block (bR,bC) owns the 256x256 tile of K at rows [256*bR,+256), cols
// [256*bC,+256). Lane (rl,cl) owns a 16x16 sub-tile.
__global__ void
__attribute__((amdgpu_flat_work_group_size(256, 256)))
__attribute__((amdgpu_waves_per_eu(1, 1)))
competitive_persistent(const float* __restrict__ AT, const float* __restrict__ BT,
                       const float* __restrict__ P,  float* __restrict__ C,
                       float* __restrict__ ws)
{
    const int b  = blockIdx.x;       // 0..255
    const int t  = threadIdx.x;      // 0..255
    const int bR = b >> 4, bC = b & 15;
    const int R0 = bR << 8, C0 = bC << 8;
    const int rl = t >> 4, cl = t & 15;
    const int row0 = R0 + rl * 16;
    const int col0 = C0 + cl * 16;

    // Barrier region (host-zeroed), beyond the 3 N-float accumulators:
    //   ws[3N + 0]           : release word (unsigned, monotonic phase count)
    //   ws[3N + 16 + b*4]    : arrival slot for block b (16 B stride)
    unsigned* relw = (unsigned*)(ws + 3 * (size_t)N);
    unsigned* arr  = (unsigned*)(ws + 3 * (size_t)N + 16);

    __shared__ __align__(16) float xsh[256];
    __shared__ __align__(16) float red[1024];
    __shared__ __align__(16) float kl[16][RLDS][256];  // 144 KiB: rows 7..15 of every lane subtile

    // ---- Load K = param^2: 7 rows/lane into registers, 9 rows/lane into LDS ----
    float k[RREG * 16];
    #pragma unroll
    for (int r = 0; r < 16; ++r) {
        const float4* src = (const float4*)(P + (size_t)(row0 + r) * N + col0);
        #pragma unroll
        for (int q = 0; q < 4; ++q) {
            float4 v = src[q];
            float4 s;
            s.x = v.x * v.x; s.y = v.y * v.y; s.z = v.z * v.z; s.w = v.w * v.w;
            if (r < RREG) {
                k[r * 16 + q * 4 + 0] = s.x;
                k[r * 16 + q * 4 + 1] = s.y;
                k[r * 16 + q * 4 + 2] = s.z;
                k[r * 16 + q * 4 + 3] = s.w;
            } else {
                *(float4*)&kl[rl][r - RREG][cl * 16 + q * 4] = s;
            }
        }
    }

    // Rotating 3-buffer scratch (each N floats, host-zeroed):
    //   phase ph accumulates into buf[ph%3], reads buf[(ph+2)%3] (== ph-1),
    //   zeroes buf[(ph+1)%3] (the accumulator of phase ph+1).
    // Phase 0 reads the zeroed buffer -> BF = BT/(1+0) = BT, matching iter 1.
    #pragma unroll 1
    for (int ph = 0; ph < NPHASE; ++ph) {
        float*       D = ws + (size_t)N * (ph % 3);
        const float* S = ws + (size_t)N * ((ph + 2) % 3);
        float*       Z = ws + (size_t)N * ((ph + 1) % 3);
        const bool rowPhase = ((ph & 1) == 0);

        // Stage x-vector slice for this block into LDS (1 divide/thread).
        {
            const int    base = rowPhase ? C0 : R0;
            const float* T    = rowPhase ? BT : AT;
            const float  s    = ld_agent(S + base + t);
            xsh[t] = T[base + t] / (1.0f + s);
        }
        // Zero the buffer phase ph+1 will accumulate into (race-free: its
        // last readers finished before the previous barrier).
        if (t < 16) st_agent(Z + b * 16 + t, 0.0f);
        __syncthreads();

        if (rowPhase) {
            // y[i] += sum_j K[i,j]*BF[j] over this lane's 16 cols
            float xv[16];
            const float4* xs4 = (const float4*)(xsh + cl * 16);
            #pragma unroll
            for (int q = 0; q < 4; ++q) {
                float4 v = xs4[q];
                xv[q * 4 + 0] = v.x; xv[q * 4 + 1] = v.y;
                xv[q * 4 + 2] = v.z; xv[q * 4 + 3] = v.w;
            }
            float part[16];
            #pragma unroll
            for (int r = 0; r < 16; ++r) part[r] = 0.0f;
            // register rows (0..6), x-broadcast major
            #pragma unroll
            for (int c = 0; c < 16; ++c) {
                const float x = xv[c];
                #pragma unroll
                for (int r = 0; r < RREG; ++r)
                    part[r] = fmaf(k[r * 16 + c], x, part[r]);
            }
            // LDS rows (7..15), row-major with b128 reads
            #pragma unroll
            for (int r = RREG; r < 16; ++r) {
                const float4* kp = (const float4*)&kl[rl][r - RREG][cl * 16];
                #pragma unroll
                for (int q = 0; q < 4; ++q) {
                    float4 kv = kp[q];
                    part[r] = fmaf(kv.x, xv[q * 4 + 0], part[r]);
                    part[r] = fmaf(kv.y, xv[q * 4 + 1], part[r]);
                    part[r] = fmaf(kv.z, xv[q * 4 + 2], part[r]);
                    part[r] = fmaf(kv.w, xv[q * 4 + 3], part[r]);
                }
            }
            // Reduce across the 16 cl-lanes (lane-id bits 0..3, in-wave).
            #pragma unroll
            for (int off = 1; off < 16; off <<= 1) {
                #pragma unroll
                for (int r = 0; r < 16; ++r)
                    part[r] += __shfl_xor(part[r], off, 64);
            }
            if (cl == 0) {
                #pragma unroll
                for (int r = 0; r < 16; ++r)
                    atomicAdd(D + row0 + r, part[r]);   // 16-way contention
            }
        } else {
            // y[j] += sum_i AF[i]*K[i,j] over this lane's 16 rows
            float av[16];
            #pragma unroll
            for (int r = 0; r < 16; ++r) av[r] = xsh[rl * 16 + r];
            float part[16];
            #pragma unroll
            for (int c = 0; c < 16; ++c) part[c] = 0.0f;
            // register rows (0..6)
            #pragma unroll
            for (int r = 0; r < RREG; ++r) {
                const float a = av[r];
                #pragma unroll
                for (int c = 0; c < 16; ++c)
                    part[c] = fmaf(k[r * 16 + c], a, part[c]);
            }
            // LDS rows (7..15)
            #pragma unroll
            for (int r = RREG; r < 16; ++r) {
                const float a = av[r];
                const float4* kp = (const float4*)&kl[rl][r - RREG][cl * 16];
                #pragma unroll
                for (int q = 0; q < 4; ++q) {
                    float4 kv = kp[q];
                    part[q * 4 + 0] = fmaf(kv.x, a, part[q * 4 + 0]);
                    part[q * 4 + 1] = fmaf(kv.y, a, part[q * 4 + 1]);
                    part[q * 4 + 2] = fmaf(kv.z, a, part[q * 4 + 2]);
                    part[q * 4 + 3] = fmaf(kv.w, a, part[q * 4 + 3]);
                }
            }
            // Reduce across rl within the wave (lane-id bits 4,5).
            #pragma unroll
            for (int c = 0; c < 16; ++c) {
                part[c] += __shfl_xor(part[c], 16, 64);
                part[c] += __shfl_xor(part[c], 32, 64);
            }
            const int w = t >> 6;                 // wave id 0..3
            if ((t & 63) < 16) {                  // one lane per cl per wave
                #pragma unroll
                for (int c = 0; c < 16; ++c)
                    red[w * 256 + cl * 16 + c] = part[c];
            }
            __syncthreads();
            const float s4 = red[t] + red[256 + t] + red[512 + t] + red[768 + t];
            atomicAdd(D + C0 + t, s4);            // 16-way contention
        }

        // ---- Grid barrier: distributed arrival slots + broadcast release ----
        __threadfence();          // release: drain this block's device-scope writes
        __syncthreads();          // whole block done
        const unsigned tgt = (unsigned)(ph + 1);
        if (b == 0) {
            // Thread t polls block t's arrival slot (t=0: block 0 is us).
            if (t != 0) {
                const unsigned* slot = arr + (size_t)t * 4;
                while (__hip_atomic_load(slot, __ATOMIC_ACQUIRE,
                                         __HIP_MEMORY_SCOPE_AGENT) < tgt)
                    __builtin_amdgcn_s_sleep(8);
            }
            __syncthreads();      // all 256 arrivals observed
            if (t == 0)
                __hip_atomic_store(relw, tgt, __ATOMIC_RELEASE,
                                   __HIP_MEMORY_SCOPE_AGENT);
        } else {
            if (t == 0) {
                __hip_atomic_store(arr + (size_t)b * 4, tgt, __ATOMIC_RELEASE,
                                   __HIP_MEMORY_SCOPE_AGENT);
                __threadfence();  // force the arrival store visible BEFORE spinning
                // Read-only spin on the broadcast word (no RMW contention).
                while (__hip_atomic_load(relw, __ATOMIC_ACQUIRE,
                                         __HIP_MEMORY_SCOPE_AGENT) < tgt)
                    __builtin_amdgcn_s_sleep(4);
            }
            __syncthreads();
        }
    }

    // ---- Epilogue: C = K * AF[:,None] * BF[None,:] ----
    // Row result of phase 40 -> buf[40%3]=buf1; col result of 41 -> buf2.
    const float* yrow = ws + (size_t)N * 1;
    const float* ycol = ws + (size_t)N * 2;
    xsh[t] = AT[R0 + t] / (1.0f + ld_agent(yrow + R0 + t));   // AF slice
    red[t] = BT[C0 + t] / (1.0f + ld_agent(ycol + C0 + t));   // BF slice
    __syncthreads();

    float af[16], bf[16];
    #pragma unroll
    for (int r = 0; r < 16; ++r) af[r] = xsh[rl * 16 + r];
    #pragma unroll
    for (int c = 0; c < 16; ++c) bf[c] = red[cl * 16 + c];

    #pragma unroll
    for (int r = 0; r < 16; ++r) {
        float4* dst = (float4*)(C + (size_t)(row0 + r) * N + col0);
        const float a = af[r];
        #pragma unroll
        for (int q = 0; q < 4; ++q) {
            float4 kv;
            if (r < RREG) {
                kv.x = k[r * 16 + q * 4 + 0];
                kv.y = k[r * 16 + q * 4 + 1];
                kv.z = k[r * 16 + q * 4 + 2];
                kv.w = k[r * 16 + q * 4 + 3];
            } else {
                kv = *(const float4*)&kl[rl][r - RREG][cl * 16 + q * 4];
            }
            float4 o;
            o.x = kv.x * a * bf[q * 4 + 0];
            o.y = kv.y * a * bf[q * 4 + 1];
            o.z = kv.z * a * bf[q * 4 + 2];
            o.w = kv.w * a * bf[q * 4 + 3];
            dst[q] = o;
        }
    }
}

extern "C" void kernel_launch(void* const* d_in, const int* in_sizes, int n_in,
                              void* d_out, int out_size, void* d_ws, size_t ws_size,
                              hipStream_t stream) {
    const float* AT = (const float*)d_in[0];
    const float* BT = (const float*)d_in[1];
    const float* P  = (const float*)d_in[2];
    float*       C  = (float*)d_out;
    float*       ws = (float*)d_ws;

    // Zero the 3 rotating accumulator buffers + barrier region
    // (release word + 256 x 16B arrival slots = 53.4 KiB total).
    // (d_ws is re-poisoned to 0xAA before every timed call.)
    hipMemsetAsync(d_ws, 0, (3 * (size_t)N + 16 + 256 * 4 + 16) * sizeof(float), stream);

    competitive_persistent<<<dim3(NBLK), dim3(256), 0, stream>>>(AT, BT, P, C, ws);
}

// Round 4
// 415.020 us; speedup vs baseline: 4.1749x; 4.1749x over previous
//
#include <hip/hip_runtime.h>

// CompetitiveLayer: K = param^2 (4096x4096 f32), 21 fixed-point iterations of
//   AF = AT/(1+K@BF); BF = BT/(1+AF@K)   -> 42 dependent matvec phases,
// then C = K * AF[:,None] * BF[None,:].
//
// R6 post-mortem chain:
//   R3: spill eliminated (VGPR 168->136, K split reg/LDS) -> time unchanged.
//   R5: barrier RMW contention eliminated (broadcast barrier) -> time
//       unchanged (1662 vs 1605). Both theories falsified.
// Invariant across ALL variants: per-phase __threadfence() + acquire/release
// device-scope atomics. On gfx950 (non-coherent per-XCD L2s) these lower to
// L2 maintenance ops (buffer_wbl2 / buffer_inv). ~128 such ops per XCD-L2
// per phase = the ~38us/phase invariant wall.
//
// R6 fix: fence-free sync. ALL cross-block ops are agent-scope RELAXED
// atomics (coherent via cache-bypass sc bits, no maintenance ops). Ordering
// "data acked before flag issued" comes from __syncthreads' built-in
// s_waitcnt vmcnt(0) drain + one explicit inline-asm vmcnt(0) (no cache
// ops). No __threadfence, no ACQUIRE/RELEASE anywhere in the loop.

constexpr int N      = 4096;
constexpr int NPHASE = 42;
constexpr int NBLK   = 256;
constexpr int RREG   = 7;           // subtile rows 0..RREG-1 in VGPRs
constexpr int RLDS   = 16 - RREG;   // subtile rows RREG..15 in LDS

__device__ __forceinline__ float ld_agent(const float* p) {
    return __hip_atomic_load(p, __ATOMIC_RELAXED, __HIP_MEMORY_SCOPE_AGENT);
}
__device__ __forceinline__ void st_agent(float* p, float v) {
    __hip_atomic_store(p, v, __ATOMIC_RELAXED, __HIP_MEMORY_SCOPE_AGENT);
}
__device__ __forceinline__ unsigned ld_flag(const unsigned* p) {
    return __hip_atomic_load(p, __ATOMIC_RELAXED, __HIP_MEMORY_SCOPE_AGENT);
}
__device__ __forceinline__ void st_flag(unsigned* p, unsigned v) {
    __hip_atomic_store(p, v, __ATOMIC_RELAXED, __HIP_MEMORY_SCOPE_AGENT);
}
// Drain all outstanding vmem ops of this wave (ack at coherence point),
// with a compile-time reordering barrier. Emits NO cache-maintenance ops.
__device__ __forceinline__ void drain_vmem() {
    asm volatile("s_waitcnt vmcnt(0)" ::: "memory");
}

// Block (bR,bC) owns the 256x256 tile of K at rows [256*bR,+256), cols
// [256*bC,+256). Lane (rl,cl) owns a 16x16 sub-tile.
__global__ void
__attribute__((amdgpu_flat_work_group_size(256, 256)))
__attribute__((amdgpu_waves_per_eu(1, 1)))
competitive_persistent(const float* __restrict__ AT, const float* __restrict__ BT,
                       const float* __restrict__ P,  float* __restrict__ C,
                       float* __restrict__ ws)
{
    const int b  = blockIdx.x;       // 0..255
    const int t  = threadIdx.x;      // 0..255
    const int bR = b >> 4, bC = b & 15;
    const int R0 = bR << 8, C0 = bC << 8;
    const int rl = t >> 4, cl = t & 15;
    const int row0 = R0 + rl * 16;
    const int col0 = C0 + cl * 16;

    // Barrier region (host-zeroed), beyond the 3 N-float accumulators:
    //   ws[3N + 0]           : release word (unsigned, monotonic phase count)
    //   ws[3N + 16 + b*4]    : arrival slot for block b (16 B stride)
    unsigned* relw = (unsigned*)(ws + 3 * (size_t)N);
    unsigned* arr  = (unsigned*)(ws + 3 * (size_t)N + 16);

    __shared__ __align__(16) float xsh[256];
    __shared__ __align__(16) float red[1024];
    __shared__ __align__(16) float kl[16][RLDS][256];  // 144 KiB: rows 7..15 of every lane subtile

    // ---- Load K = param^2: 7 rows/lane into registers, 9 rows/lane into LDS ----
    float k[RREG * 16];
    #pragma unroll
    for (int r = 0; r < 16; ++r) {
        const float4* src = (const float4*)(P + (size_t)(row0 + r) * N + col0);
        #pragma unroll
        for (int q = 0; q < 4; ++q) {
            float4 v = src[q];
            float4 s;
            s.x = v.x * v.x; s.y = v.y * v.y; s.z = v.z * v.z; s.w = v.w * v.w;
            if (r < RREG) {
                k[r * 16 + q * 4 + 0] = s.x;
                k[r * 16 + q * 4 + 1] = s.y;
                k[r * 16 + q * 4 + 2] = s.z;
                k[r * 16 + q * 4 + 3] = s.w;
            } else {
                *(float4*)&kl[rl][r - RREG][cl * 16 + q * 4] = s;
            }
        }
    }

    // Rotating 3-buffer scratch (each N floats, host-zeroed):
    //   phase ph accumulates into buf[ph%3], reads buf[(ph+2)%3] (== ph-1),
    //   zeroes buf[(ph+1)%3] (the accumulator of phase ph+1).
    // Phase 0 reads the zeroed buffer -> BF = BT/(1+0) = BT, matching iter 1.
    #pragma unroll 1
    for (int ph = 0; ph < NPHASE; ++ph) {
        float*       D = ws + (size_t)N * (ph % 3);
        const float* S = ws + (size_t)N * ((ph + 2) % 3);
        float*       Z = ws + (size_t)N * ((ph + 1) % 3);
        const bool rowPhase = ((ph & 1) == 0);

        // Stage x-vector slice for this block into LDS (1 divide/thread).
        {
            const int    base = rowPhase ? C0 : R0;
            const float* T    = rowPhase ? BT : AT;
            const float  s    = ld_agent(S + base + t);
            xsh[t] = T[base + t] / (1.0f + s);
        }
        // Zero the buffer phase ph+1 will accumulate into (race-free: its
        // last readers finished before the previous barrier).
        if (t < 16) st_agent(Z + b * 16 + t, 0.0f);
        __syncthreads();

        if (rowPhase) {
            // y[i] += sum_j K[i,j]*BF[j] over this lane's 16 cols
            float xv[16];
            const float4* xs4 = (const float4*)(xsh + cl * 16);
            #pragma unroll
            for (int q = 0; q < 4; ++q) {
                float4 v = xs4[q];
                xv[q * 4 + 0] = v.x; xv[q * 4 + 1] = v.y;
                xv[q * 4 + 2] = v.z; xv[q * 4 + 3] = v.w;
            }
            float part[16];
            #pragma unroll
            for (int r = 0; r < 16; ++r) part[r] = 0.0f;
            // register rows (0..6), x-broadcast major
            #pragma unroll
            for (int c = 0; c < 16; ++c) {
                const float x = xv[c];
                #pragma unroll
                for (int r = 0; r < RREG; ++r)
                    part[r] = fmaf(k[r * 16 + c], x, part[r]);
            }
            // LDS rows (7..15), row-major with b128 reads
            #pragma unroll
            for (int r = RREG; r < 16; ++r) {
                const float4* kp = (const float4*)&kl[rl][r - RREG][cl * 16];
                #pragma unroll
                for (int q = 0; q < 4; ++q) {
                    float4 kv = kp[q];
                    part[r] = fmaf(kv.x, xv[q * 4 + 0], part[r]);
                    part[r] = fmaf(kv.y, xv[q * 4 + 1], part[r]);
                    part[r] = fmaf(kv.z, xv[q * 4 + 2], part[r]);
                    part[r] = fmaf(kv.w, xv[q * 4 + 3], part[r]);
                }
            }
            // Reduce across the 16 cl-lanes (lane-id bits 0..3, in-wave).
            #pragma unroll
            for (int off = 1; off < 16; off <<= 1) {
                #pragma unroll
                for (int r = 0; r < 16; ++r)
                    part[r] += __shfl_xor(part[r], off, 64);
            }
            if (cl == 0) {
                #pragma unroll
                for (int r = 0; r < 16; ++r)
                    atomicAdd(D + row0 + r, part[r]);   // relaxed agent RMW
            }
        } else {
            // y[j] += sum_i AF[i]*K[i,j] over this lane's 16 rows
            float av[16];
            #pragma unroll
            for (int r = 0; r < 16; ++r) av[r] = xsh[rl * 16 + r];
            float part[16];
            #pragma unroll
            for (int c = 0; c < 16; ++c) part[c] = 0.0f;
            // register rows (0..6)
            #pragma unroll
            for (int r = 0; r < RREG; ++r) {
                const float a = av[r];
                #pragma unroll
                for (int c = 0; c < 16; ++c)
                    part[c] = fmaf(k[r * 16 + c], a, part[c]);
            }
            // LDS rows (7..15)
            #pragma unroll
            for (int r = RREG; r < 16; ++r) {
                const float a = av[r];
                const float4* kp = (const float4*)&kl[rl][r - RREG][cl * 16];
                #pragma unroll
                for (int q = 0; q < 4; ++q) {
                    float4 kv = kp[q];
                    part[q * 4 + 0] = fmaf(kv.x, a, part[q * 4 + 0]);
                    part[q * 4 + 1] = fmaf(kv.y, a, part[q * 4 + 1]);
                    part[q * 4 + 2] = fmaf(kv.z, a, part[q * 4 + 2]);
                    part[q * 4 + 3] = fmaf(kv.w, a, part[q * 4 + 3]);
                }
            }
            // Reduce across rl within the wave (lane-id bits 4,5).
            #pragma unroll
            for (int c = 0; c < 16; ++c) {
                part[c] += __shfl_xor(part[c], 16, 64);
                part[c] += __shfl_xor(part[c], 32, 64);
            }
            const int w = t >> 6;                 // wave id 0..3
            if ((t & 63) < 16) {                  // one lane per cl per wave
                #pragma unroll
                for (int c = 0; c < 16; ++c)
                    red[w * 256 + cl * 16 + c] = part[c];
            }
            __syncthreads();
            const float s4 = red[t] + red[256 + t] + red[512 + t] + red[768 + t];
            atomicAdd(D + C0 + t, s4);            // relaxed agent RMW
        }

        // ---- Grid barrier: fence-free (relaxed flags + vmcnt drains) ----
        // __syncthreads emits s_waitcnt vmcnt(0) lgkmcnt(0) before s_barrier:
        // every wave's data-atomics are acked at the coherence point before
        // any flag store below issues. No cache-maintenance ops anywhere.
        __syncthreads();
        const unsigned tgt = (unsigned)(ph + 1);
        if (b == 0) {
            // Thread t polls block t's arrival slot (t=0: block 0 is us).
            if (t != 0) {
                const unsigned* slot = arr + (size_t)t * 4;
                while (ld_flag(slot) < tgt)
                    __builtin_amdgcn_s_sleep(8);
            }
            asm volatile("" ::: "memory");   // pin polls before release
            __syncthreads();                 // all 256 arrivals observed
            if (t == 0)
                st_flag(relw, tgt);
        } else {
            if (t == 0) {
                st_flag(arr + (size_t)b * 4, tgt);
                drain_vmem();                // arrival store acked before spin
                while (ld_flag(relw) < tgt)
                    __builtin_amdgcn_s_sleep(4);
                asm volatile("" ::: "memory");
            }
            __syncthreads();
        }
    }

    // ---- Epilogue: C = K * AF[:,None] * BF[None,:] ----
    // Row result of phase 40 -> buf[40%3]=buf1; col result of 41 -> buf2.
    const float* yrow = ws + (size_t)N * 1;
    const float* ycol = ws + (size_t)N * 2;
    xsh[t] = AT[R0 + t] / (1.0f + ld_agent(yrow + R0 + t));   // AF slice
    red[t] = BT[C0 + t] / (1.0f + ld_agent(ycol + C0 + t));   // BF slice
    __syncthreads();

    float af[16], bf[16];
    #pragma unroll
    for (int r = 0; r < 16; ++r) af[r] = xsh[rl * 16 + r];
    #pragma unroll
    for (int c = 0; c < 16; ++c) bf[c] = red[cl * 16 + c];

    #pragma unroll
    for (int r = 0; r < 16; ++r) {
        float4* dst = (float4*)(C + (size_t)(row0 + r) * N + col0);
        const float a = af[r];
        #pragma unroll
        for (int q = 0; q < 4; ++q) {
            float4 kv;
            if (r < RREG) {
                kv.x = k[r * 16 + q * 4 + 0];
                kv.y = k[r * 16 + q * 4 + 1];
                kv.z = k[r * 16 + q * 4 + 2];
                kv.w = k[r * 16 + q * 4 + 3];
            } else {
                kv = *(const float4*)&kl[rl][r - RREG][cl * 16 + q * 4];
            }
            float4 o;
            o.x = kv.x * a * bf[q * 4 + 0];
            o.y = kv.y * a * bf[q * 4 + 1];
            o.z = kv.z * a * bf[q * 4 + 2];
            o.w = kv.w * a * bf[q * 4 + 3];
            dst[q] = o;
        }
    }
}

extern "C" void kernel_launch(void* const* d_in, const int* in_sizes, int n_in,
                              void* d_out, int out_size, void* d_ws, size_t ws_size,
                              hipStream_t stream) {
    const float* AT = (const float*)d_in[0];
    const float* BT = (const float*)d_in[1];
    const float* P  = (const float*)d_in[2];
    float*       C  = (float*)d_out;
    float*       ws = (float*)d_ws;

    // Zero the 3 rotating accumulator buffers + barrier region
    // (release word + 256 x 16B arrival slots).
    // (d_ws is re-poisoned to 0xAA before every timed call.)
    hipMemsetAsync(d_ws, 0, (3 * (size_t)N + 16 + 256 * 4 + 16) * sizeof(float), stream);

    competitive_persistent<<<dim3(NBLK), dim3(256), 0, stream>>>(AT, BT, P, C, ws);
}

// Round 5
// 400.008 us; speedup vs baseline: 4.3316x; 1.0375x over previous
//
#include <hip/hip_runtime.h>

// CompetitiveLayer: K = param^2 (4096x4096 f32), 21 iterations of
//   AF = AT/(1+K@BF); BF = BT/(1+AF@K), then C = K*AF[:,None]*BF[None,:].
//
// R6 post-mortem: fence-free sync (relaxed agent atomics + vmcnt drains, no
// threadfence/acq/rel) took 1662 -> 325us. CONFIRMED: gfx950 lowers ordered
// agent atomics to L2 maintenance ops; those were ~30us/phase. Remaining
// 7.7us/phase = atomic-ack -> GLOBAL 3-hop barrier (+max-of-256 jitter) ->
// stage read.
//
// R7: group-local sync. y_row[R0..R0+255] is produced AND consumed only by
// row-group bR (blocks (bR,*)); y_col[C0..+255] only by col-group bC. So:
//   - 16-block group barriers (arrival flag + direct 16-lane poll; 2 hops,
//     no central release; groups drift independently -> jitter absorbed,
//     cross-group pipelining).
//   - y_row[3][4096], y_col[3][4096] mod-3 rotation; each block zeroes its
//     16-elem share of buffer (it+2)%3 right AFTER its group wait. Ordering:
//     zero -> (drain) -> own arrival flag(level it+1) -> next writers' group
//     wait observes that flag before touching the buffer. All relaxed agent
//     ops + vmcnt drains (R6-validated discipline); zero cache-maintenance.

constexpr int N     = 4096;
constexpr int NITER = 21;
constexpr int NBLK  = 256;
constexpr int RREG  = 7;           // subtile rows 0..RREG-1 in VGPRs
constexpr int RLDS  = 16 - RREG;   // subtile rows RREG..15 in LDS

__device__ __forceinline__ float ld_agent(const float* p) {
    return __hip_atomic_load(p, __ATOMIC_RELAXED, __HIP_MEMORY_SCOPE_AGENT);
}
__device__ __forceinline__ void st_agent(float* p, float v) {
    __hip_atomic_store(p, v, __ATOMIC_RELAXED, __HIP_MEMORY_SCOPE_AGENT);
}
__device__ __forceinline__ unsigned ld_flag(const unsigned* p) {
    return __hip_atomic_load(p, __ATOMIC_RELAXED, __HIP_MEMORY_SCOPE_AGENT);
}
__device__ __forceinline__ void st_flag(unsigned* p, unsigned v) {
    __hip_atomic_store(p, v, __ATOMIC_RELAXED, __HIP_MEMORY_SCOPE_AGENT);
}
// Drain this wave's outstanding vmem (ack at coherence point). No cache ops.
__device__ __forceinline__ void drain_vmem() {
    asm volatile("s_waitcnt vmcnt(0)" ::: "memory");
}

// Block (bR,bC) owns the 256x256 tile of K. Lane (rl,cl) owns a 16x16 sub-tile.
__global__ void
__attribute__((amdgpu_flat_work_group_size(256, 256)))
__attribute__((amdgpu_waves_per_eu(1, 1)))
competitive_persistent(const float* __restrict__ AT, const float* __restrict__ BT,
                       const float* __restrict__ P,  float* __restrict__ C,
                       float* __restrict__ ws)
{
    const int b  = blockIdx.x;       // 0..255
    const int t  = threadIdx.x;      // 0..255
    const int bR = b >> 4, bC = b & 15;
    const int R0 = bR << 8, C0 = bC << 8;
    const int rl = t >> 4, cl = t & 15;
    const int row0 = R0 + rl * 16;
    const int col0 = C0 + cl * 16;

    // ws layout (all host-zeroed):
    //   y_row[3][4096]  at ws[0)        -- row-group-private accumulators
    //   y_col[3][4096]  at ws[3N)       -- col-group-private accumulators
    //   flag_row[256]   at ws[6N), 16B-strided uints (slot g = frow + g*4)
    //   flag_col[256]   at ws[6N)+4KB
    float*    yrow = ws;
    float*    ycol = ws + 3 * (size_t)N;
    unsigned* frow = (unsigned*)(ws + 6 * (size_t)N);
    unsigned* fcol = frow + 1024;

    __shared__ __align__(16) float xsh[256];
    __shared__ __align__(16) float red[1024];
    __shared__ __align__(16) float kl[16][RLDS][256];  // 144 KiB: rows 7..15

    // ---- Load K = param^2: 7 rows/lane in registers, 9 rows/lane in LDS ----
    float k[RREG * 16];
    #pragma unroll
    for (int r = 0; r < 16; ++r) {
        const float4* src = (const float4*)(P + (size_t)(row0 + r) * N + col0);
        #pragma unroll
        for (int q = 0; q < 4; ++q) {
            float4 v = src[q];
            float4 s;
            s.x = v.x * v.x; s.y = v.y * v.y; s.z = v.z * v.z; s.w = v.w * v.w;
            if (r < RREG) {
                k[r * 16 + q * 4 + 0] = s.x;
                k[r * 16 + q * 4 + 1] = s.y;
                k[r * 16 + q * 4 + 2] = s.z;
                k[r * 16 + q * 4 + 3] = s.w;
            } else {
                *(float4*)&kl[rl][r - RREG][cl * 16 + q * 4] = s;
            }
        }
    }

    #pragma unroll 1
    for (int it = 0; it < NITER; ++it) {
        const unsigned lvl = (unsigned)(it + 1);

        // ---- W1: wait col-group bC at level it (y_col[(it+2)%3] ready) ----
        if (t < 64) {
            const unsigned* f = fcol + (size_t)bC * 64 + (size_t)(t & 15) * 4;
            while (ld_flag(f) < (unsigned)it) __builtin_amdgcn_s_sleep(2);
        }
        __syncthreads();
        // Z1: zero my 16-elem share of y_col[(it+1)%3] (group-private range;
        // last readers proven done by W1; visible to next writers via my C4 flag).
        if (t < 16)
            st_agent(ycol + (size_t)((it + 1) % 3) * N + C0 + bR * 16 + t, 0.0f);
        // R2: stage BF = BT/(1+y_col_prev)
        {
            const float s = ld_agent(ycol + (size_t)((it + 2) % 3) * N + C0 + t);
            xsh[t] = BT[C0 + t] / (1.0f + s);
        }
        __syncthreads();

        // ---- R3: rowPhase  y_row[i] += sum_j K[i,j]*BF[j] ----
        {
            float* D = yrow + (size_t)(it % 3) * N;
            float xv[16];
            const float4* xs4 = (const float4*)(xsh + cl * 16);
            #pragma unroll
            for (int q = 0; q < 4; ++q) {
                float4 v = xs4[q];
                xv[q * 4 + 0] = v.x; xv[q * 4 + 1] = v.y;
                xv[q * 4 + 2] = v.z; xv[q * 4 + 3] = v.w;
            }
            float part[16];
            #pragma unroll
            for (int r = 0; r < 16; ++r) part[r] = 0.0f;
            #pragma unroll
            for (int c = 0; c < 16; ++c) {
                const float x = xv[c];
                #pragma unroll
                for (int r = 0; r < RREG; ++r)
                    part[r] = fmaf(k[r * 16 + c], x, part[r]);
            }
            #pragma unroll
            for (int r = RREG; r < 16; ++r) {
                const float4* kp = (const float4*)&kl[rl][r - RREG][cl * 16];
                #pragma unroll
                for (int q = 0; q < 4; ++q) {
                    float4 kv = kp[q];
                    part[r] = fmaf(kv.x, xv[q * 4 + 0], part[r]);
                    part[r] = fmaf(kv.y, xv[q * 4 + 1], part[r]);
                    part[r] = fmaf(kv.z, xv[q * 4 + 2], part[r]);
                    part[r] = fmaf(kv.w, xv[q * 4 + 3], part[r]);
                }
            }
            #pragma unroll
            for (int off = 1; off < 16; off <<= 1) {
                #pragma unroll
                for (int r = 0; r < 16; ++r)
                    part[r] += __shfl_xor(part[r], off, 64);
            }
            if (cl == 0) {
                #pragma unroll
                for (int r = 0; r < 16; ++r)
                    atomicAdd(D + row0 + r, part[r]);   // relaxed agent RMW
            }
        }
        // Arrival: all waves drained their atomics at barrier entry.
        __syncthreads();
        if (t == 0) { drain_vmem(); st_flag(frow + (size_t)b * 4, lvl); }

        // ---- W2: wait row-group bR at level it+1 (y_row[it%3] complete) ----
        if (t < 64) {
            const unsigned* f = frow + (size_t)bR * 64 + (size_t)(t & 15) * 4;
            while (ld_flag(f) < lvl) __builtin_amdgcn_s_sleep(2);
        }
        __syncthreads();
        // Z2: zero my 16-elem share of y_row[(it+2)%3]
        if (t < 16)
            st_agent(yrow + (size_t)((it + 2) % 3) * N + R0 + bC * 16 + t, 0.0f);
        // C2: stage AF = AT/(1+y_row)
        {
            const float s = ld_agent(yrow + (size_t)(it % 3) * N + R0 + t);
            xsh[t] = AT[R0 + t] / (1.0f + s);
        }
        __syncthreads();

        // ---- C3: colPhase  y_col[j] += sum_i AF[i]*K[i,j] ----
        {
            float* D = ycol + (size_t)(it % 3) * N;
            float av[16];
            #pragma unroll
            for (int r = 0; r < 16; ++r) av[r] = xsh[rl * 16 + r];
            float part[16];
            #pragma unroll
            for (int c = 0; c < 16; ++c) part[c] = 0.0f;
            #pragma unroll
            for (int r = 0; r < RREG; ++r) {
                const float a = av[r];
                #pragma unroll
                for (int c = 0; c < 16; ++c)
                    part[c] = fmaf(k[r * 16 + c], a, part[c]);
            }
            #pragma unroll
            for (int r = RREG; r < 16; ++r) {
                const float a = av[r];
                const float4* kp = (const float4*)&kl[rl][r - RREG][cl * 16];
                #pragma unroll
                for (int q = 0; q < 4; ++q) {
                    float4 kv = kp[q];
                    part[q * 4 + 0] = fmaf(kv.x, a, part[q * 4 + 0]);
                    part[q * 4 + 1] = fmaf(kv.y, a, part[q * 4 + 1]);
                    part[q * 4 + 2] = fmaf(kv.z, a, part[q * 4 + 2]);
                    part[q * 4 + 3] = fmaf(kv.w, a, part[q * 4 + 3]);
                }
            }
            #pragma unroll
            for (int c = 0; c < 16; ++c) {
                part[c] += __shfl_xor(part[c], 16, 64);
                part[c] += __shfl_xor(part[c], 32, 64);
            }
            const int w = t >> 6;
            if ((t & 63) < 16) {
                #pragma unroll
                for (int c = 0; c < 16; ++c)
                    red[w * 256 + cl * 16 + c] = part[c];
            }
            __syncthreads();
            const float s4 = red[t] + red[256 + t] + red[512 + t] + red[768 + t];
            atomicAdd(D + C0 + t, s4);                  // relaxed agent RMW
        }
        __syncthreads();
        if (t == 0) { drain_vmem(); st_flag(fcol + (size_t)(bC * 16 + bR) * 4, lvl); }
    }

    // ---- Final wait: col-group at level NITER (y_col[2] complete) ----
    if (t < 64) {
        const unsigned* f = fcol + (size_t)bC * 64 + (size_t)(t & 15) * 4;
        while (ld_flag(f) < (unsigned)NITER) __builtin_amdgcn_s_sleep(2);
    }
    __syncthreads();

    // ---- Epilogue: C = K * AF[:,None] * BF[None,:]  (it=20 -> buf 20%3=2) ----
    xsh[t] = AT[R0 + t] / (1.0f + ld_agent(yrow + 2 * (size_t)N + R0 + t));
    red[t] = BT[C0 + t] / (1.0f + ld_agent(ycol + 2 * (size_t)N + C0 + t));
    __syncthreads();

    float af[16], bf[16];
    #pragma unroll
    for (int r = 0; r < 16; ++r) af[r] = xsh[rl * 16 + r];
    #pragma unroll
    for (int c = 0; c < 16; ++c) bf[c] = red[cl * 16 + c];

    #pragma unroll
    for (int r = 0; r < 16; ++r) {
        float4* dst = (float4*)(C + (size_t)(row0 + r) * N + col0);
        const float a = af[r];
        #pragma unroll
        for (int q = 0; q < 4; ++q) {
            float4 kv;
            if (r < RREG) {
                kv.x = k[r * 16 + q * 4 + 0];
                kv.y = k[r * 16 + q * 4 + 1];
                kv.z = k[r * 16 + q * 4 + 2];
                kv.w = k[r * 16 + q * 4 + 3];
            } else {
                kv = *(const float4*)&kl[rl][r - RREG][cl * 16 + q * 4];
            }
            float4 o;
            o.x = kv.x * a * bf[q * 4 + 0];
            o.y = kv.y * a * bf[q * 4 + 1];
            o.z = kv.z * a * bf[q * 4 + 2];
            o.w = kv.w * a * bf[q * 4 + 3];
            dst[q] = o;
        }
    }
}

extern "C" void kernel_launch(void* const* d_in, const int* in_sizes, int n_in,
                              void* d_out, int out_size, void* d_ws, size_t ws_size,
                              hipStream_t stream) {
    const float* AT = (const float*)d_in[0];
    const float* BT = (const float*)d_in[1];
    const float* P  = (const float*)d_in[2];
    float*       C  = (float*)d_out;
    float*       ws = (float*)d_ws;

    // Zero y_row[3][4096] + y_col[3][4096] + 2x256 16B-strided flags
    // (6*4096 + 2048 floats = 104 KiB). d_ws re-poisoned before every call.
    hipMemsetAsync(d_ws, 0, (6 * (size_t)N + 2048) * sizeof(float), stream);

    competitive_persistent<<<dim3(NBLK), dim3(256), 0, stream>>>(AT, BT, P, C, ws);
}